// Round 10
// baseline (280.970 us; speedup 1.0000x reference)
//
#include <hip/hip_runtime.h>
#include <hip/hip_cooperative_groups.h>
namespace cg = cooperative_groups;

constexpr int ATOM = 34;
constexpr int HID = 256;
constexpr int LATENT = 128;
constexpr int CELLS = 512;
constexpr int NN = 128;
constexpr int NA = NN * ATOM;   // 4352
#define NEGF (-9e15f)

// ---- LDS pool layout (floats) ----
// GAT:     xl[128][36]@0..4608, hlT[34][132]@4608..9096, att[32][132]@9096..13320,
//          wgT[34][36]@13320..14544, mask u64[32][2]@14544..14672, fs@14672, fd@14800..14928
// phaseB:  wt[256][36]@0..9216 (pl overlay after weights dead), wf[256][36]@9216..18432,
//          dlT[34][33]@18432..19554, sl[512]@19554..20066
// survives GAT->phaseB: xq[32][36]@20100..21252
// decoder: vec[640]@0, dsl[512]@640, h1[128]@1152, h2[256]@1280
constexpr int P_XL   = 0;
constexpr int P_HLT  = 4608;
constexpr int P_ATT  = 9096;
constexpr int P_WGT  = 13320;
constexpr int P_MASK = 14544;
constexpr int P_FS   = 14672;
constexpr int P_FD   = 14800;
constexpr int P_WT   = 0;
constexpr int P_WF   = 9216;
constexpr int P_DLT  = 18432;
constexpr int P_SL   = 19554;
constexpr int P_XQ   = 20100;
constexpr int P_VEC  = 0;
constexpr int P_DSL  = 640;
constexpr int P_H1   = 1152;
constexpr int P_H2   = 1280;
constexpr int POOL   = 21252;   // 85.0 KB -> 1 block/CU, 256 blocks co-resident

__global__ __launch_bounds__(512) void mega(
    const float* __restrict__ xs, const int* __restrict__ A,
    const float* __restrict__ cell,
    const float* __restrict__ Wg3, const float* __restrict__ bg3,
    const float* __restrict__ av3,
    const float* __restrict__ Wt, const float* __restrict__ bt,
    const float* __restrict__ Wf, const float* __restrict__ bf,
    const float* __restrict__ Wf2, const float* __restrict__ bf2,
    const float* __restrict__ W1, const float* __restrict__ b1,
    const float* __restrict__ W2, const float* __restrict__ b2,
    const float* __restrict__ W3, const float* __restrict__ b3,
    const float* __restrict__ W4, const float* __restrict__ b4,
    float* __restrict__ out, float* __restrict__ X0, float* __restrict__ X1,
    float* __restrict__ DM)
{
    cg::grid_group grid = cg::this_grid();
    __shared__ __align__(16) float pool[POOL];
    const int bid = blockIdx.x, b = bid >> 2, q4 = bid & 3;
    const int t = threadIdx.x, lane = t & 63, wave = t >> 6;
    const int p0 = q4 * 32;

    float* xl  = pool + P_XL;
    float* hlT = pool + P_HLT;
    float* att = pool + P_ATT;
    float* wgT = pool + P_WGT;
    unsigned long long* mask = (unsigned long long*)(pool + P_MASK);
    float* fs  = pool + P_FS;
    float* fd  = pool + P_FD;
    float* xq  = pool + P_XQ;

    // xl pads (persist; staging rewrites only cols 0..33)
    if (t < 256) xl[(t >> 1) * 36 + 34 + (t & 1)] = 0.f;

    // =================== 3 GAT rounds ===================
    for (int r = 0; r < 3; ++r) {
        const float* Wgr = Wg3 + r * ATOM * ATOM;
        const float* bgr = bg3 + r * ATOM;
        const float* avr = av3 + r * 2 * ATOM;
        const float* xsrc = (r == 0) ? (xs + b * NA) : (((r == 1) ? X0 : X1) + b * NA);

        // stage x + wgT (transposed, zero-padded)
        for (int i = t; i < NA; i += 512) xl[(i / ATOM) * 36 + (i % ATOM)] = xsrc[i];
        for (int i = t; i < ATOM * ATOM; i += 512) {
            int d = i / ATOM, e = i - d * ATOM;
            wgT[e * 36 + d] = Wgr[i];
        }
        if (t < 68) wgT[(t >> 1) * 36 + 34 + (t & 1)] = 0.f;
        __syncthreads();

        // h^T = relu(x@Wg+bg)^T : n = t>>2, sub = t&3 (8-9 e's each); wg 4-addr broadcast
        {
            const int n = t >> 2, sub = t & 3;
            float xr[36];
            {
                float4* x4 = (float4*)xr;
                const float4* p4 = (const float4*)(xl + n * 36);
                #pragma unroll
                for (int k = 0; k < 9; ++k) x4[k] = p4[k];
            }
            #pragma unroll
            for (int j = 0; j < 9; ++j) {
                const int e = sub + 4 * j;
                if (e < ATOM) {
                    float acc = bgr[e];
                    const float4* wp = (const float4*)(wgT + e * 36);
                    #pragma unroll
                    for (int k = 0; k < 9; ++k) {
                        float4 w = wp[k];
                        acc += xr[4*k] * w.x + xr[4*k+1] * w.y + xr[4*k+2] * w.z + xr[4*k+3] * w.w;
                    }
                    hlT[e * 132 + n] = fmaxf(acc, 0.f);
                }
            }
        }
        __syncthreads();

        // fs/fd (first 256 threads)
        if (t < 2 * NN) {
            const int n = t & 127, w = t >> 7;
            const float* avp = avr + w * ATOM;
            float acc = 0.f;
            #pragma unroll
            for (int d = 0; d < ATOM; ++d) acc += hlT[d * 132 + n] * avp[d];
            if (w == 0) fs[n] = acc; else fd[n] = acc;
        }
        __syncthreads();

        // masked softmax: 8 waves x 4 rows; masks built in r0, cached in LDS
        const int* Ab = A + b * NN * NN;
        #pragma unroll
        for (int i = 0; i < 4; ++i) {
            const int lp = wave * 4 + i, gp = p0 + lp;
            unsigned long long m0, m1;
            if (r == 0) {
                m0 = __ballot(Ab[gp * NN + lane] > 0);
                m1 = __ballot(Ab[gp * NN + 64 + lane] > 0);
                if (lane == 0) { mask[lp * 2] = m0; mask[lp * 2 + 1] = m1; }
            } else {
                m0 = mask[lp * 2]; m1 = mask[lp * 2 + 1];
            }
            const float fsv = fs[gp];
            float s0 = fsv + fd[lane];
            s0 = (s0 > 0.f) ? s0 : 0.01f * s0;
            if (!((m0 >> lane) & 1ull)) s0 = NEGF;
            float s1 = fsv + fd[64 + lane];
            s1 = (s1 > 0.f) ? s1 : 0.01f * s1;
            if (!((m1 >> lane) & 1ull)) s1 = NEGF;
            float mx = fmaxf(s0, s1);
            #pragma unroll
            for (int o = 32; o >= 1; o >>= 1) mx = fmaxf(mx, __shfl_xor(mx, o, 64));
            float e0 = __expf(s0 - mx), e1 = __expf(s1 - mx);
            float sm = e0 + e1;
            #pragma unroll
            for (int o = 32; o >= 1; o >>= 1) sm += __shfl_xor(sm, o, 64);
            float inv = 1.f / sm;
            att[lp * 132 + lane]      = e0 * inv;
            att[lp * 132 + 64 + lane] = e1 * inv;
        }
        __syncthreads();

        // x_out = x + att@h : p = t>>4 (32 rows), g = t&15
        {
            const int p = t >> 4, g = t & 15, gp = p0 + p;
            const float4* ap  = (const float4*)(att + p * 132);
            const float4* h1p = (const float4*)(hlT + g * 132);
            const float4* h2p = (const float4*)(hlT + (g + 16) * 132);
            float a1 = 0.f, a2 = 0.f;
            #pragma unroll 8
            for (int k = 0; k < 32; ++k) {
                float4 a4 = ap[k], x1 = h1p[k], x2 = h2p[k];
                a1 += a4.x * x1.x + a4.y * x1.y + a4.z * x1.z + a4.w * x1.w;
                a2 += a4.x * x2.x + a4.y * x2.y + a4.z * x2.z + a4.w * x2.w;
            }
            float a3 = 0.f;
            if (g < 2) {
                const float4* h3p = (const float4*)(hlT + (g + 32) * 132);
                #pragma unroll 8
                for (int k = 0; k < 32; ++k) {
                    float4 a4 = ap[k], x3 = h3p[k];
                    a3 += a4.x * x3.x + a4.y * x3.y + a4.z * x3.z + a4.w * x3.w;
                }
            }
            if (r < 2) {
                float* Xr = ((r == 0) ? X0 : X1) + b * NA + gp * ATOM;
                Xr[g]      = xl[gp * 36 + g] + a1;
                Xr[g + 16] = xl[gp * 36 + g + 16] + a2;
                if (g < 2) Xr[g + 32] = xl[gp * 36 + g + 32] + a3;
            } else {                                  // round 3: keep in LDS
                xq[p * 36 + g]      = xl[gp * 36 + g] + a1;
                xq[p * 36 + g + 16] = xl[gp * 36 + g + 16] + a2;
                if (g < 2) {
                    xq[p * 36 + g + 32] = xl[gp * 36 + g + 32] + a3;
                    xq[p * 36 + 34 + g] = 0.f;        // zero pads
                }
            }
        }
        if (r < 2) grid.sync();
    }
    __syncthreads();     // xq ready; GAT regions dead -> overlay

    // =================== phaseB (round-4 proven 1-row body) ===================
    float* wt  = pool + P_WT;
    float* wf  = pool + P_WF;
    float* dlT = pool + P_DLT;
    float* sl  = pool + P_SL;

    for (int i = t; i < ATOM * HID; i += 512) {
        int d = i >> 8, h = i & 255;               // Wt is [d][h]
        wt[h * 36 + d] = Wt[i];
    }
    for (int i = t; i < HID * ATOM; i += 512) {
        int h = i / ATOM, j = i - (i / ATOM) * ATOM; // Wf is [h][j]
        wf[h * 36 + j] = Wf[i];
    }
    wt[(t >> 1) * 36 + 34 + (t & 1)] = 0.f;        // zero pads (512 = 256h x 2)
    wf[(t >> 1) * 36 + 34 + (t & 1)] = 0.f;
    __syncthreads();

    {
        const int row = t & 31, sub = t >> 5;      // sub 0..15
        float dp[ATOM];
        #pragma unroll
        for (int j = 0; j < ATOM; ++j) dp[j] = 0.f;
        {
            float xr[36];
            float4* xr4 = (float4*)xr;
            const float4* xlr = (const float4*)(xq + row * 36);
            #pragma unroll
            for (int k = 0; k < 9; ++k) xr4[k] = xlr[k];
            for (int i = 0; i < 16; ++i) {
                const int h = sub + 16 * i;
                float acc = bt[h];
                const float4* wtp = (const float4*)(wt + h * 36);
                #pragma unroll
                for (int k = 0; k < 9; ++k) {
                    float4 w4 = wtp[k];
                    acc += xr[4*k] * w4.x + xr[4*k+1] * w4.y + xr[4*k+2] * w4.z + xr[4*k+3] * w4.w;
                }
                acc = fmaxf(acc, 0.f);
                const float4* wfp = (const float4*)(wf + h * 36);
                #pragma unroll
                for (int k = 0; k < 8; ++k) {
                    float4 w4 = wfp[k];
                    dp[4*k]   += acc * w4.x; dp[4*k+1] += acc * w4.y;
                    dp[4*k+2] += acc * w4.z; dp[4*k+3] += acc * w4.w;
                }
                dp[32] += acc * wf[h * 36 + 32];
                dp[33] += acc * wf[h * 36 + 33];
            }
        }
        __syncthreads();                           // wt/wf weights consumed
        float* pl = (sub < 8) ? wt : wf;           // partials overlay
        const int s8 = sub & 7;
        #pragma unroll
        for (int j = 0; j < ATOM; ++j) pl[(s8 * 32 + row) * ATOM + j] = dp[j];
    }
    __syncthreads();

    // d = sum(partials) + bf + xs ; store transposed
    {
        const float* xsq = xs + b * NA + p0 * ATOM;
        for (int i = t; i < 32 * ATOM; i += 512) {
            int rr = i / ATOM, j = i - (i / ATOM) * ATOM;
            float dv = bf[j] + xsq[rr * ATOM + j];
            #pragma unroll
            for (int s = 0; s < 8; ++s)
                dv += wt[(s * 32 + rr) * ATOM + j] + wf[(s * 32 + rr) * ATOM + j];
            dlT[j * 33 + rr] = dv;
        }
    }
    __syncthreads();

    // d @ Wf2 + bf2 ; partial col-max (4 chunks x 8 rows)
    {
        const int l = t & 127, chunk = t >> 7;
        float w2r[ATOM];
        #pragma unroll
        for (int j = 0; j < ATOM; ++j) w2r[j] = Wf2[j * LATENT + l];
        const float bb = bf2[l];
        float mx = -3.4e38f;
        #pragma unroll
        for (int r8 = 0; r8 < 8; ++r8) {
            const int rr = chunk * 8 + r8;
            float acc = bb;
            #pragma unroll
            for (int j = 0; j < ATOM; ++j) acc += dlT[j * 33 + rr] * w2r[j];
            mx = fmaxf(mx, acc);
        }
        sl[chunk * 128 + l] = mx;
    }
    __syncthreads();
    if (t < LATENT)
        DM[(b * 4 + q4) * LATENT + t] =
            fmaxf(fmaxf(sl[t], sl[128 + t]), fmaxf(sl[256 + t], sl[384 + t]));

    grid.sync();

    // =================== decoder (blocks with q4==0) ===================
    if (q4 != 0) return;
    float* vec = pool + P_VEC;
    float* dsl = pool + P_DSL;
    float* h1  = pool + P_H1;
    float* h2  = pool + P_H2;

    if (t < LATENT) {
        float m = fmaxf(fmaxf(DM[(b*4+0)*LATENT + t], DM[(b*4+1)*LATENT + t]),
                        fmaxf(DM[(b*4+2)*LATENT + t], DM[(b*4+3)*LATENT + t]));
        vec[t] = 1.f / (1.f + __expf(-m));
    }
    vec[LATENT + t] = 1.f / (1.f + __expf(-cell[b * CELLS + t]));
    __syncthreads();
    {   // L1: 640->128, 4-way k-split
        const int j = t & 127, part = t >> 7;
        float acc = 0.f;
        #pragma unroll 8
        for (int k = part * 160; k < part * 160 + 160; ++k)
            acc += vec[k] * W1[k * 128 + j];
        dsl[part * 128 + j] = acc;
    }
    __syncthreads();
    if (t < 128)
        h1[t] = fmaxf(dsl[t] + dsl[128 + t] + dsl[256 + t] + dsl[384 + t] + b1[t], 0.f);
    __syncthreads();
    {   // L2: 128->256, 2-way k-split
        const int j = t & 255, half = t >> 8;
        float acc = 0.f;
        #pragma unroll 8
        for (int k = half * 64; k < half * 64 + 64; ++k)
            acc += h1[k] * W2[k * 256 + j];
        dsl[half * 256 + j] = acc;
    }
    __syncthreads();
    if (t < 256) h2[t] = fmaxf(dsl[t] + dsl[256 + t] + b2[t], 0.f);
    __syncthreads();
    {   // L3 + L4
        float acc = b3[t];
        #pragma unroll 8
        for (int k = 0; k < 256; ++k) acc += h2[k] * W3[k * 512 + t];
        float v = fmaxf(acc, 0.f) * W4[t];
        #pragma unroll
        for (int o = 32; o >= 1; o >>= 1) v += __shfl_xor(v, o, 64);
        if (lane == 0) dsl[wave] = v;
    }
    __syncthreads();
    if (t == 0) {
        float s = b4[0];
        #pragma unroll
        for (int w = 0; w < 8; ++w) s += dsl[w];
        out[b] = s;
    }
}

extern "C" void kernel_launch(void* const* d_in, const int* in_sizes, int n_in,
                              void* d_out, int out_size, void* d_ws, size_t ws_size,
                              hipStream_t stream) {
    const float* xs       = (const float*)d_in[0];
    const int*   A        = (const int*)  d_in[1];
    const float* cell_emb = (const float*)d_in[2];
    const float* Wg       = (const float*)d_in[3];
    const float* bg       = (const float*)d_in[4];
    const float* attnv    = (const float*)d_in[5];
    const float* Wt       = (const float*)d_in[6];
    const float* bt       = (const float*)d_in[7];
    const float* Wf       = (const float*)d_in[8];
    const float* bf       = (const float*)d_in[9];
    const float* Wf2      = (const float*)d_in[10];
    const float* bf2      = (const float*)d_in[11];
    const float* W1       = (const float*)d_in[12];
    const float* b1       = (const float*)d_in[13];
    const float* W2       = (const float*)d_in[14];
    const float* b2       = (const float*)d_in[15];
    const float* W3       = (const float*)d_in[16];
    const float* b3       = (const float*)d_in[17];
    const float* W4       = (const float*)d_in[18];
    const float* b4       = (const float*)d_in[19];
    float* out = (float*)d_out;

    float* Wsp = (float*)d_ws;
    float* X0 = Wsp;                 // 278528
    float* X1 = Wsp + 278528;        // 278528
    float* DM = Wsp + 557056;        // 32768

    void* kargs[] = {
        (void*)&xs, (void*)&A, (void*)&cell_emb,
        (void*)&Wg, (void*)&bg, (void*)&attnv,
        (void*)&Wt, (void*)&bt, (void*)&Wf, (void*)&bf,
        (void*)&Wf2, (void*)&bf2,
        (void*)&W1, (void*)&b1, (void*)&W2, (void*)&b2,
        (void*)&W3, (void*)&b3, (void*)&W4, (void*)&b4,
        (void*)&out, (void*)&X0, (void*)&X1, (void*)&DM
    };
    hipLaunchCooperativeKernel((void*)mega, dim3(256), dim3(512), kargs, 0, stream);
}

// Round 11
// 168.235 us; speedup vs baseline: 1.6701x; 1.6701x over previous
//
#include <hip/hip_runtime.h>

constexpr int ATOM = 34;
constexpr int HID = 256;
constexpr int LATENT = 128;
constexpr int CELLS = 512;
constexpr int NN = 128;
constexpr int NA = NN * ATOM;   // 4352
#define NEGF (-9e15f)

// ---------------- K1: fused GAT round ----------------
// grid 256 = 64 batches x 4 slices of 32 rows, block 512 (8 waves).
// R==0: build adjacency ballots, store to Mm.  R>0: s_load masks from Mm.
template <int R>
__global__ __launch_bounds__(512) void k_gat(
    const float* __restrict__ xsrc, const int* __restrict__ A,
    unsigned long long* __restrict__ Mm,
    const float* __restrict__ Wgr, const float* __restrict__ bgr,
    const float* __restrict__ avr, float* __restrict__ X)
{
    const int b = blockIdx.x >> 2, q4 = blockIdx.x & 3;
    const int t = threadIdx.x, lane = t & 63, wave = t >> 6;
    const int p0 = q4 * 32;

    __shared__ __align__(16) float xl[NN * 36];      // 18.4 KB
    __shared__ __align__(16) float hlT[ATOM * 132];  // 17.9 KB  h transposed
    __shared__ __align__(16) float att[32 * 132];    // 16.9 KB  stride 132
    __shared__ __align__(16) float wgT[ATOM * 36];   // 4.9 KB
    __shared__ float fs[NN], fd[NN];

    // ---- stage x + wgT ----
    const float* xp = xsrc + b * NA;
    for (int i = t; i < NA; i += 512) xl[(i / ATOM) * 36 + (i % ATOM)] = xp[i];
    if (t < 256) xl[(t >> 1) * 36 + 34 + (t & 1)] = 0.f;    // zero pads
    for (int i = t; i < ATOM * ATOM; i += 512) {
        int d = i / ATOM, e = i - d * ATOM;
        wgT[e * 36 + d] = Wgr[i];
    }
    if (t < 68) wgT[(t >> 1) * 36 + 34 + (t & 1)] = 0.f;
    __syncthreads();

    // ---- h^T = relu(x@Wg+bg)^T : n = t>>2 (all 128 rows), sub = t&3 ----
    {
        const int n = t >> 2, sub = t & 3;
        float xr[36];
        {
            float4* x4 = (float4*)xr;
            const float4* p4 = (const float4*)(xl + n * 36);
            #pragma unroll
            for (int k = 0; k < 9; ++k) x4[k] = p4[k];
        }
        #pragma unroll
        for (int j = 0; j < 9; ++j) {
            const int e = sub + 4 * j;
            if (e < ATOM) {
                float acc = bgr[e];
                const float4* wp = (const float4*)(wgT + e * 36);
                #pragma unroll
                for (int k = 0; k < 9; ++k) {
                    float4 w = wp[k];
                    acc += xr[4*k] * w.x + xr[4*k+1] * w.y + xr[4*k+2] * w.z + xr[4*k+3] * w.w;
                }
                hlT[e * 132 + n] = fmaxf(acc, 0.f);
            }
        }
    }
    __syncthreads();

    // ---- fs/fd (first 256 threads; av via s_load, wave-uniform w) ----
    if (t < 2 * NN) {
        const int n = t & 127, w = t >> 7;
        const float* avp = avr + w * ATOM;
        float acc = 0.f;
        #pragma unroll
        for (int d = 0; d < ATOM; ++d) acc += hlT[d * 132 + n] * avp[d];
        if (w == 0) fs[n] = acc; else fd[n] = acc;
    }
    __syncthreads();

    // ---- masked softmax: 8 waves x 4 rows ----
    const int* Ab = A + b * NN * NN;
    unsigned long long* Mb = Mm + b * NN * 2;
    #pragma unroll
    for (int i = 0; i < 4; ++i) {
        const int lp = wave * 4 + i, gp = p0 + lp;
        unsigned long long m0, m1;
        if (R == 0) {
            m0 = __ballot(Ab[gp * NN + lane] > 0);
            m1 = __ballot(Ab[gp * NN + 64 + lane] > 0);
            if (lane == 0) { Mb[gp * 2] = m0; Mb[gp * 2 + 1] = m1; }
        } else {
            m0 = Mb[gp * 2];          // wave-uniform -> s_load
            m1 = Mb[gp * 2 + 1];
        }
        const float fsv = fs[gp];
        float s0 = fsv + fd[lane];
        s0 = (s0 > 0.f) ? s0 : 0.01f * s0;
        if (!((m0 >> lane) & 1ull)) s0 = NEGF;
        float s1 = fsv + fd[64 + lane];
        s1 = (s1 > 0.f) ? s1 : 0.01f * s1;
        if (!((m1 >> lane) & 1ull)) s1 = NEGF;
        float mx = fmaxf(s0, s1);
        #pragma unroll
        for (int o = 32; o >= 1; o >>= 1) mx = fmaxf(mx, __shfl_xor(mx, o, 64));
        float e0 = __expf(s0 - mx), e1 = __expf(s1 - mx);
        float sm = e0 + e1;
        #pragma unroll
        for (int o = 32; o >= 1; o >>= 1) sm += __shfl_xor(sm, o, 64);
        float inv = 1.f / sm;
        att[lp * 132 + lane]      = e0 * inv;
        att[lp * 132 + 64 + lane] = e1 * inv;
    }
    __syncthreads();

    // ---- x_out = x + att@h : register-blocked 2 rows x 2 cols x k-half ----
    // thread (pq = t>>5, g = (t>>1)&15, kh = t&1): rows {2pq,2pq+1}, cols {g,g+16}
    {
        const int pq = t >> 5, g = (t >> 1) & 15, kh = t & 1;
        const int rA = 2 * pq, rB = rA + 1;
        const float4* apA = (const float4*)(att + rA * 132 + kh * 64);
        const float4* apB = (const float4*)(att + rB * 132 + kh * 64);
        const float4* hA  = (const float4*)(hlT + g * 132 + kh * 64);
        const float4* hB  = (const float4*)(hlT + (g + 16) * 132 + kh * 64);
        float aAA = 0.f, aAB = 0.f, aBA = 0.f, aBB = 0.f;
        #pragma unroll
        for (int k = 0; k < 16; ++k) {
            float4 a0 = apA[k], a1 = apB[k], h0 = hA[k], h1 = hB[k];
            aAA += a0.x * h0.x + a0.y * h0.y + a0.z * h0.z + a0.w * h0.w;
            aAB += a0.x * h1.x + a0.y * h1.y + a0.z * h1.z + a0.w * h1.w;
            aBA += a1.x * h0.x + a1.y * h0.y + a1.z * h0.z + a1.w * h0.w;
            aBB += a1.x * h1.x + a1.y * h1.y + a1.z * h1.z + a1.w * h1.w;
        }
        aAA += __shfl_xor(aAA, 1, 64);
        aAB += __shfl_xor(aAB, 1, 64);
        aBA += __shfl_xor(aBA, 1, 64);
        aBB += __shfl_xor(aBB, 1, 64);
        if (kh == 0) {
            const int gpA = p0 + rA, gpB = p0 + rB;
            float* XrA = X + b * NA + gpA * ATOM;
            float* XrB = X + b * NA + gpB * ATOM;
            XrA[g]      = xl[gpA * 36 + g] + aAA;
            XrA[g + 16] = xl[gpA * 36 + g + 16] + aAB;
            XrB[g]      = xl[gpB * 36 + g] + aBA;
            XrB[g + 16] = xl[gpB * 36 + g + 16] + aBB;
        }
    }
    // tail: cols 32/33 for all 32 rows (threads 0..127)
    if (t < 128) {
        const int p = t >> 2, c = 32 + ((t >> 1) & 1), kh = t & 1;
        const float4* ap = (const float4*)(att + p * 132 + kh * 64);
        const float4* hp = (const float4*)(hlT + c * 132 + kh * 64);
        float a = 0.f;
        #pragma unroll
        for (int k = 0; k < 16; ++k) {
            float4 a4 = ap[k], h4 = hp[k];
            a += a4.x * h4.x + a4.y * h4.y + a4.z * h4.z + a4.w * h4.w;
        }
        a += __shfl_xor(a, 1, 64);
        if (kh == 0) {
            const int gp = p0 + p;
            X[b * NA + gp * ATOM + c] = xl[gp * 36 + c] + a;
        }
    }
}

// ---------------- K2: phaseB (r6 proven body) ----------------
__global__ __launch_bounds__(512, 1) void k_phaseB(
    const float* __restrict__ X, const float* __restrict__ xs,
    const float* __restrict__ Wt, const float* __restrict__ bt,
    const float* __restrict__ Wf, const float* __restrict__ bf,
    const float* __restrict__ Wf2, const float* __restrict__ bf2,
    float* __restrict__ DM)
{
    const int b = blockIdx.x >> 2, q4 = blockIdx.x & 3;
    const int t = threadIdx.x;
    const int p0 = q4 * 32;
    __shared__ __align__(16) float wt[HID * 36];
    __shared__ __align__(16) float wf[HID * 36];
    __shared__ __align__(16) float xl[32 * 36];
    __shared__ float dlT[ATOM * 33];
    __shared__ float sl[512];

    for (int i = t; i < ATOM * HID; i += 512) {
        int d = i >> 8, h = i & 255;
        wt[h * 36 + d] = Wt[i];
    }
    for (int i = t; i < HID * ATOM; i += 512) {
        int h = i / ATOM, j = i - (i / ATOM) * ATOM;
        wf[h * 36 + j] = Wf[i];
    }
    wt[(t >> 1) * 36 + 34 + (t & 1)] = 0.f;
    wf[(t >> 1) * 36 + 34 + (t & 1)] = 0.f;
    for (int i = t; i < 32 * ATOM; i += 512) xl[(i / ATOM) * 36 + (i % ATOM)] = X[b * NA + p0 * ATOM + i];
    if (t < 64) xl[(t >> 1) * 36 + 34 + (t & 1)] = 0.f;
    __syncthreads();

    {
        const int row = t & 31, sub = t >> 5;
        float dp[ATOM];
        #pragma unroll
        for (int j = 0; j < ATOM; ++j) dp[j] = 0.f;
        {
            float xr[36];
            float4* xr4 = (float4*)xr;
            const float4* xlr = (const float4*)(xl + row * 36);
            #pragma unroll
            for (int k = 0; k < 9; ++k) xr4[k] = xlr[k];
            for (int i = 0; i < 16; ++i) {
                const int h = sub + 16 * i;
                float acc = bt[h];
                const float4* wtp = (const float4*)(wt + h * 36);
                #pragma unroll
                for (int k = 0; k < 9; ++k) {
                    float4 w4 = wtp[k];
                    acc += xr[4*k] * w4.x + xr[4*k+1] * w4.y + xr[4*k+2] * w4.z + xr[4*k+3] * w4.w;
                }
                acc = fmaxf(acc, 0.f);
                const float4* wfp = (const float4*)(wf + h * 36);
                #pragma unroll
                for (int k = 0; k < 8; ++k) {
                    float4 w4 = wfp[k];
                    dp[4*k]   += acc * w4.x; dp[4*k+1] += acc * w4.y;
                    dp[4*k+2] += acc * w4.z; dp[4*k+3] += acc * w4.w;
                }
                dp[32] += acc * wf[h * 36 + 32];
                dp[33] += acc * wf[h * 36 + 33];
            }
        }
        __syncthreads();
        float* pl = (sub < 8) ? wt : wf;
        const int s8 = sub & 7;
        #pragma unroll
        for (int j = 0; j < ATOM; ++j) pl[(s8 * 32 + row) * ATOM + j] = dp[j];
    }
    __syncthreads();

    {
        const float* xsq = xs + b * NA + p0 * ATOM;
        for (int i = t; i < 32 * ATOM; i += 512) {
            int rr = i / ATOM, j = i - (i / ATOM) * ATOM;
            float dv = bf[j] + xsq[rr * ATOM + j];
            #pragma unroll
            for (int s = 0; s < 8; ++s)
                dv += wt[(s * 32 + rr) * ATOM + j] + wf[(s * 32 + rr) * ATOM + j];
            dlT[j * 33 + rr] = dv;
        }
    }
    __syncthreads();

    {
        const int l = t & 127, chunk = t >> 7;
        float w2r[ATOM];
        #pragma unroll
        for (int j = 0; j < ATOM; ++j) w2r[j] = Wf2[j * LATENT + l];
        const float bb = bf2[l];
        float mx = -3.4e38f;
        #pragma unroll
        for (int r8 = 0; r8 < 8; ++r8) {
            const int rr = chunk * 8 + r8;
            float acc = bb;
            #pragma unroll
            for (int j = 0; j < ATOM; ++j) acc += dlT[j * 33 + rr] * w2r[j];
            mx = fmaxf(mx, acc);
        }
        sl[chunk * 128 + l] = mx;
    }
    __syncthreads();
    if (t < LATENT)
        DM[(b * 4 + q4) * LATENT + t] =
            fmaxf(fmaxf(sl[t], sl[128 + t]), fmaxf(sl[256 + t], sl[384 + t]));
}

// ---------------- K3: full decoder (r6 proven body) ----------------
__global__ __launch_bounds__(1024) void k_dec(
    const float* __restrict__ DM, const float* __restrict__ cell,
    const float* __restrict__ W1, const float* __restrict__ b1,
    const float* __restrict__ W2, const float* __restrict__ b2,
    const float* __restrict__ W3, const float* __restrict__ b3,
    const float* __restrict__ W4, const float* __restrict__ b4,
    float* __restrict__ out)
{
    const int b = blockIdx.x, t = threadIdx.x, lane = t & 63, wave = t >> 6;
    __shared__ float vec[LATENT + CELLS];
    __shared__ float h1[128], h2[256], h3[512];
    __shared__ float sl[1024];
    if (t < LATENT) {
        float m = fmaxf(fmaxf(DM[(b*4+0)*LATENT + t], DM[(b*4+1)*LATENT + t]),
                        fmaxf(DM[(b*4+2)*LATENT + t], DM[(b*4+3)*LATENT + t]));
        vec[t] = 1.f / (1.f + __expf(-m));
    } else if (t >= 512) {
        int c = t - 512;
        vec[LATENT + c] = 1.f / (1.f + __expf(-cell[b * CELLS + c]));
    }
    __syncthreads();
    {
        const int j = t & 127, part = t >> 7;
        float acc = 0.f;
        #pragma unroll 4
        for (int k = part * 80; k < part * 80 + 80; ++k)
            acc += vec[k] * W1[k * 128 + j];
        sl[part * 128 + j] = acc;
    }
    __syncthreads();
    if (t < 128) {
        float v = b1[t];
        #pragma unroll
        for (int p = 0; p < 8; ++p) v += sl[p * 128 + t];
        h1[t] = fmaxf(v, 0.f);
    }
    __syncthreads();
    {
        const int j = t & 255, part = t >> 8;
        float acc = 0.f;
        #pragma unroll 4
        for (int k = part * 32; k < part * 32 + 32; ++k)
            acc += h1[k] * W2[k * 256 + j];
        sl[part * 256 + j] = acc;
    }
    __syncthreads();
    if (t < 256) h2[t] = fmaxf(sl[t] + sl[256 + t] + sl[512 + t] + sl[768 + t] + b2[t], 0.f);
    __syncthreads();
    {
        const int j = t & 511, part = t >> 9;
        float acc = 0.f;
        #pragma unroll 4
        for (int k = part * 128; k < part * 128 + 128; ++k)
            acc += h2[k] * W3[k * 512 + j];
        sl[part * 512 + j] = acc;
    }
    __syncthreads();
    if (t < 512) h3[t] = fmaxf(sl[t] + sl[512 + t] + b3[t], 0.f);
    __syncthreads();
    float v = (t < 512) ? h3[t] * W4[t] : 0.f;
    #pragma unroll
    for (int o = 32; o >= 1; o >>= 1) v += __shfl_xor(v, o, 64);
    if (lane == 0) sl[wave] = v;
    __syncthreads();
    if (t == 0) {
        float s = b4[0];
        #pragma unroll
        for (int w = 0; w < 16; ++w) s += sl[w];
        out[b] = s;
    }
}

extern "C" void kernel_launch(void* const* d_in, const int* in_sizes, int n_in,
                              void* d_out, int out_size, void* d_ws, size_t ws_size,
                              hipStream_t stream) {
    const float* xs       = (const float*)d_in[0];
    const int*   A        = (const int*)  d_in[1];
    const float* cell_emb = (const float*)d_in[2];
    const float* Wg       = (const float*)d_in[3];
    const float* bg       = (const float*)d_in[4];
    const float* attnv    = (const float*)d_in[5];
    const float* Wt       = (const float*)d_in[6];
    const float* bt       = (const float*)d_in[7];
    const float* Wf       = (const float*)d_in[8];
    const float* bf       = (const float*)d_in[9];
    const float* Wf2      = (const float*)d_in[10];
    const float* bf2      = (const float*)d_in[11];
    const float* W1       = (const float*)d_in[12];
    const float* b1       = (const float*)d_in[13];
    const float* W2       = (const float*)d_in[14];
    const float* b2       = (const float*)d_in[15];
    const float* W3       = (const float*)d_in[16];
    const float* b3       = (const float*)d_in[17];
    const float* W4       = (const float*)d_in[18];
    const float* b4       = (const float*)d_in[19];
    float* out = (float*)d_out;

    float* Wsp = (float*)d_ws;
    float* X0 = Wsp;                                                // 278528
    float* X1 = Wsp + 278528;                                       // 278528
    float* DM = Wsp + 557056;                                       // 32768
    unsigned long long* Mm = (unsigned long long*)(Wsp + 589824);   // 16384 u64

    k_gat<0><<<256, 512, 0, stream>>>(xs, A, Mm, Wg,                   bg,      attnv,       X0);
    k_gat<1><<<256, 512, 0, stream>>>(X0, A, Mm, Wg + ATOM * ATOM,     bg + 34, attnv + 68,  X1);
    k_gat<1><<<256, 512, 0, stream>>>(X1, A, Mm, Wg + 2 * ATOM * ATOM, bg + 68, attnv + 136, X0);
    k_phaseB<<<256, 512, 0, stream>>>(X0, xs, Wt, bt, Wf, bf, Wf2, bf2, DM);
    k_dec<<<64, 1024, 0, stream>>>(DM, cell_emb, W1, b1, W2, b2, W3, b3, W4, b4, out);
}